// Round 13
// baseline (223.562 us; speedup 1.0000x reference)
//
#include <hip/hip_runtime.h>
#include <cstdint>
#include <cstddef>

#define HID 128
#define LDK 72    // GEMM LDS row stride in bf16 elems (64 + 8 pad)
#define EPB 4096  // edges per block in bucket pass
#define CAP 8192  // per-bucket capacity in ebuf/csr16 (mean load 4096, sigma ~64)

typedef __attribute__((ext_vector_type(8))) short short8;
typedef __attribute__((ext_vector_type(4))) float floatx4;

#if __has_builtin(__builtin_amdgcn_cvt_pk_f32_fp8) && __has_builtin(__builtin_amdgcn_cvt_pk_fp8_f32)
#define HW_FP8 1
#else
#define HW_FP8 0
#endif

__device__ __forceinline__ unsigned short f2bf(float f) {
  union { float f; uint32_t u; } c; c.f = f;
  uint32_t u = c.u;
  uint32_t r = (u + 0x7FFFu + ((u >> 16) & 1u)) >> 16;   // RNE
  return (unsigned short)r;
}
__device__ __forceinline__ float bf2f(unsigned short s) { return __uint_as_float(((uint32_t)s) << 16); }
// truncating f32->bf16 pair pack — EXACT for fp8-derived values (3-bit mantissa)
__device__ __forceinline__ uint32_t pkbf(float a, float b) {
  return (__float_as_uint(a) >> 16) | (__float_as_uint(b) & 0xFFFF0000u);
}

// Software fp8 e4m3 (OCP) fallback — only used if HW cvt builtins are absent.
__device__ __forceinline__ uint32_t f2fp8_sw(float v) {
  uint32_t u = __float_as_uint(v);
  uint32_t s = (u >> 24) & 0x80u;
  uint32_t af = u & 0x7FFFFFFFu;
  if (__uint_as_float(af) < 0.015625f) return s;
  uint32_t r = af + 0x7FFFFu + ((af >> 20) & 1u);
  return s | ((r >> 20) - 960u);
}
__device__ __forceinline__ float fp8dec_sw(uint32_t b) {
  uint32_t mag = b & 0x7Fu;
  uint32_t v = ((b & 0x80u) << 24) | ((mag << 20) + 0x3C000000u);
  return mag ? __uint_as_float(v) : 0.0f;
}

__device__ __forceinline__ uint32_t pack_fp8x4(float a, float b, float c, float d) {
#if HW_FP8
  int p = __builtin_amdgcn_cvt_pk_fp8_f32(a, b, 0, false);
  p = __builtin_amdgcn_cvt_pk_fp8_f32(c, d, p, true);
  return (uint32_t)p;
#else
  return f2fp8_sw(a) | (f2fp8_sw(b) << 8) | (f2fp8_sw(c) << 16) | (f2fp8_sw(d) << 24);
#endif
}

__device__ __forceinline__ unsigned char f2fp8_one(float v) {
#if HW_FP8
  return (unsigned char)(__builtin_amdgcn_cvt_pk_fp8_f32(v, v, 0, false) & 0xFF);
#else
  return (unsigned char)f2fp8_sw(v);
#endif
}

// accumulate 4 fp8 bytes (one dword) into a[0..3]
__device__ __forceinline__ void acc_fp8x4(float* __restrict__ a, uint32_t w) {
#if HW_FP8
  auto lo = __builtin_amdgcn_cvt_pk_f32_fp8(w, false);
  auto hi = __builtin_amdgcn_cvt_pk_f32_fp8(w, true);
  a[0] += lo[0]; a[1] += lo[1]; a[2] += hi[0]; a[3] += hi[1];
#else
  a[0] += fp8dec_sw(w & 255);
  a[1] += fp8dec_sw((w >> 8) & 255);
  a[2] += fp8dec_sw((w >> 16) & 255);
  a[3] += fp8dec_sw(w >> 24);
#endif
}

// 8 fp8 bytes (uint2) -> 8 bf16 (uint4), lossless expansion
__device__ __forceinline__ uint4 fp8x8_to_bf16x8(uint2 w) {
#if HW_FP8
  auto f01 = __builtin_amdgcn_cvt_pk_f32_fp8(w.x, false);
  auto f23 = __builtin_amdgcn_cvt_pk_f32_fp8(w.x, true);
  auto f45 = __builtin_amdgcn_cvt_pk_f32_fp8(w.y, false);
  auto f67 = __builtin_amdgcn_cvt_pk_f32_fp8(w.y, true);
  uint4 o;
  o.x = pkbf(f01[0], f01[1]);
  o.y = pkbf(f23[0], f23[1]);
  o.z = pkbf(f45[0], f45[1]);
  o.w = pkbf(f67[0], f67[1]);
  return o;
#else
  uint4 o;
  o.x = pkbf(fp8dec_sw(w.x & 255), fp8dec_sw((w.x >> 8) & 255));
  o.y = pkbf(fp8dec_sw((w.x >> 16) & 255), fp8dec_sw(w.x >> 24));
  o.z = pkbf(fp8dec_sw(w.y & 255), fp8dec_sw((w.y >> 8) & 255));
  o.w = pkbf(fp8dec_sw((w.y >> 16) & 255), fp8dec_sw(w.y >> 24));
  return o;
#endif
}

// ---------------- merged prologue: bucket pass + x fp8 cast + weight bf16 cast ----------------
// Blocks [0, bktBlocks): group edges by dst>>8 into per-bucket CAP regions.
// Blocks [bktBlocks, bktBlocks+castBlocks): cast x fp32 -> fp8.
// Blocks [bktBlocks+castBlocks, +64): cast 4 weight matrices fp32 -> bf16 (RNE).

__global__ __launch_bounds__(256) void k_prologue(const int* __restrict__ src,
                                                  const int* __restrict__ dst,
                                                  int* __restrict__ bcur,
                                                  uint32_t* __restrict__ ebuf,
                                                  int E, int NB,
                                                  const float* __restrict__ x,
                                                  uint32_t* __restrict__ xq,
                                                  int n4, int bktBlocks, int castBlocks,
                                                  const float* __restrict__ wl1,
                                                  const float* __restrict__ wr1,
                                                  const float* __restrict__ wl2,
                                                  const float* __restrict__ wr2,
                                                  unsigned short* __restrict__ wb) {
  const int t = threadIdx.x;
  const int bx = (int)blockIdx.x;
  if (bx >= bktBlocks + castBlocks) {
    // weight cast: 16 blocks per matrix, 4096 threads/matrix, 4 elems/thread
    int wblk = bx - bktBlocks - castBlocks;     // 0..63
    int mat = wblk >> 4;
    const float* wsrc = (mat == 0) ? wl1 : (mat == 1) ? wr1 : (mat == 2) ? wl2 : wr2;
    int i = ((wblk & 15) * 256 + t);            // 0..4095, elems 4i..4i+3
    float4 v = ((const float4*)wsrc)[i];
    uint32_t lo = (uint32_t)f2bf(v.x) | ((uint32_t)f2bf(v.y) << 16);
    uint32_t hi = (uint32_t)f2bf(v.z) | ((uint32_t)f2bf(v.w) << 16);
    ((uint2*)(wb + (size_t)mat * HID * HID))[i] = make_uint2(lo, hi);
    return;
  }
  if (bx >= bktBlocks) {
    int i = (bx - bktBlocks) * 256 + t;
    if (i < n4) {
      float4 v = ((const float4*)x)[i];
      xq[i] = pack_fp8x4(v.x, v.y, v.z, v.w);
    }
    return;
  }
  __shared__ int hist[256];
  __shared__ int lcur[256];
  const int base = bx * EPB;
  hist[t] = 0;
  __syncthreads();

  uint32_t val[EPB / 256];
  int bk[EPB / 256];
  #pragma unroll
  for (int i = 0; i < EPB / 256; ++i) {
    int e = base + i * 256 + t;
    bk[i] = -1;
    if (e < E) {
      int d = dst[e];
      int s = src[e];
      bk[i] = d >> 8;
      val[i] = (uint32_t)s | ((uint32_t)(d & 255) << 16);
      atomicAdd(&hist[bk[i]], 1);
    }
  }
  __syncthreads();
  if (t < NB) {
    int c = hist[t];
    lcur[t] = c ? atomicAdd(&bcur[t], c) : 0;
  }
  __syncthreads();
  #pragma unroll
  for (int i = 0; i < EPB / 256; ++i) {
    if (bk[i] >= 0) {
      int pos = bk[i] * CAP + atomicAdd(&lcur[bk[i]], 1);
      ebuf[pos] = val[i];
    }
  }
}

// fill pass: one block per bucket; builds rowbeg/rowend + csr16 in CAP region.
__global__ __launch_bounds__(256) void k_bucket_fill2(const uint32_t* __restrict__ ebuf,
                                                      const int* __restrict__ bcur,
                                                      int* __restrict__ rowbeg,
                                                      int* __restrict__ rowend,
                                                      unsigned short* __restrict__ csr16,
                                                      int N) {
  __shared__ int hist[256];
  __shared__ int scan[256];
  const int b = blockIdx.x;
  const int t = threadIdx.x;
  hist[t] = 0;
  __syncthreads();
  const int lo = b * CAP;
  const int hi = lo + bcur[b];
  for (int i = lo + t; i < hi; i += 256) atomicAdd(&hist[ebuf[i] >> 16], 1);
  __syncthreads();
  int v = hist[t];
  scan[t] = v;
  __syncthreads();
  #pragma unroll
  for (int off = 1; off < 256; off <<= 1) {
    int add = (t >= off) ? scan[t - off] : 0;
    __syncthreads();
    scan[t] += add;
    __syncthreads();
  }
  int excl = scan[t] - v;
  int node = (b << 8) + t;
  if (node < N) {
    rowbeg[node] = lo + excl;
    rowend[node] = lo + excl + v;
  }
  hist[t] = lo + excl;   // reuse as cursor
  __syncthreads();
  for (int i = lo + t; i < hi; i += 256) {
    uint32_t e = ebuf[i];
    int pos = atomicAdd(&hist[e >> 16], 1);
    csr16[pos] = (unsigned short)(e & 0xFFFFu);
  }
}

// ---------------- mean aggregation: one wave per TWO nodes, fp8 in/out ----------------

__global__ __launch_bounds__(256) void k_aggregate(const unsigned char* __restrict__ featq,
                                                   const int* __restrict__ rowbeg,
                                                   const int* __restrict__ rowend,
                                                   const unsigned short* __restrict__ csr16,
                                                   unsigned char* __restrict__ outmean, int N) {
  int wpair = blockIdx.x * 4 + (threadIdx.x >> 6);
  int n0 = wpair * 2;
  int n1 = n0 + 1;
  int lane = threadIdx.x & 63;
  if (n0 >= N) return;
  const int grp = lane >> 4;
  const int fl  = lane & 15;

  int b0 = rowbeg[n0], e0 = rowend[n0];
  int b1 = 0, e1 = 0;
  if (n1 < N) { b1 = rowbeg[n1]; e1 = rowend[n1]; }
  const int d0 = e0 - b0, d1 = e1 - b1;

  float a0[8], a1[8];
  #pragma unroll
  for (int i = 0; i < 8; ++i) { a0[i] = 0.f; a1[i] = 0.f; }

  while (b0 < e0 || b1 < e1) {
    int m0 = e0 - b0; if (m0 < 0) m0 = 0; if (m0 > 64) m0 = 64;
    int m1 = e1 - b1; if (m1 < 0) m1 = 0; if (m1 > 64) m1 = 64;
    int sidx0 = (b0 + lane < e0) ? (int)csr16[b0 + lane] : 0;
    int sidx1 = (b1 + lane < e1) ? (int)csr16[b1 + lane] : 0;
    int mm = m0 > m1 ? m0 : m1;
    for (int j = 0; j < mm; j += 16) {
      int j0 = j + grp, j1 = j + grp + 4, j2 = j + grp + 8, j3 = j + grp + 12;
      int s00 = __shfl(sidx0, j0, 64), s01 = __shfl(sidx0, j1, 64);
      int s02 = __shfl(sidx0, j2, 64), s03 = __shfl(sidx0, j3, 64);
      int s10 = __shfl(sidx1, j0, 64), s11 = __shfl(sidx1, j1, 64);
      int s12 = __shfl(sidx1, j2, 64), s13 = __shfl(sidx1, j3, 64);
      bool p00 = j0 < m0, p01 = j1 < m0, p02 = j2 < m0, p03 = j3 < m0;
      bool p10 = j0 < m1, p11 = j1 < m1, p12 = j2 < m1, p13 = j3 < m1;
      uint2 u00, u01, u02, u03, u10, u11, u12, u13;
      if (p00) u00 = *(const uint2*)(featq + (size_t)s00 * HID + fl * 8);
      if (p01) u01 = *(const uint2*)(featq + (size_t)s01 * HID + fl * 8);
      if (p02) u02 = *(const uint2*)(featq + (size_t)s02 * HID + fl * 8);
      if (p03) u03 = *(const uint2*)(featq + (size_t)s03 * HID + fl * 8);
      if (p10) u10 = *(const uint2*)(featq + (size_t)s10 * HID + fl * 8);
      if (p11) u11 = *(const uint2*)(featq + (size_t)s11 * HID + fl * 8);
      if (p12) u12 = *(const uint2*)(featq + (size_t)s12 * HID + fl * 8);
      if (p13) u13 = *(const uint2*)(featq + (size_t)s13 * HID + fl * 8);
      if (p00) { acc_fp8x4(a0, u00.x); acc_fp8x4(a0 + 4, u00.y); }
      if (p01) { acc_fp8x4(a0, u01.x); acc_fp8x4(a0 + 4, u01.y); }
      if (p02) { acc_fp8x4(a0, u02.x); acc_fp8x4(a0 + 4, u02.y); }
      if (p03) { acc_fp8x4(a0, u03.x); acc_fp8x4(a0 + 4, u03.y); }
      if (p10) { acc_fp8x4(a1, u10.x); acc_fp8x4(a1 + 4, u10.y); }
      if (p11) { acc_fp8x4(a1, u11.x); acc_fp8x4(a1 + 4, u11.y); }
      if (p12) { acc_fp8x4(a1, u12.x); acc_fp8x4(a1 + 4, u12.y); }
      if (p13) { acc_fp8x4(a1, u13.x); acc_fp8x4(a1 + 4, u13.y); }
    }
    b0 += 64; b1 += 64;
  }

  #pragma unroll
  for (int i = 0; i < 8; ++i) {
    a0[i] += __shfl_xor(a0[i], 16, 64);
    a0[i] += __shfl_xor(a0[i], 32, 64);
    a1[i] += __shfl_xor(a1[i], 16, 64);
    a1[i] += __shfl_xor(a1[i], 32, 64);
  }
  if (grp == 0) {
    float inv0 = 1.0f / (float)(d0 > 1 ? d0 : 1);
    uint2 o;
    o.x = pack_fp8x4(a0[0] * inv0, a0[1] * inv0, a0[2] * inv0, a0[3] * inv0);
    o.y = pack_fp8x4(a0[4] * inv0, a0[5] * inv0, a0[6] * inv0, a0[7] * inv0);
    *(uint2*)(outmean + (size_t)n0 * HID + fl * 8) = o;
    if (n1 < N) {
      float inv1 = 1.0f / (float)(d1 > 1 ? d1 : 1);
      uint2 p;
      p.x = pack_fp8x4(a1[0] * inv1, a1[1] * inv1, a1[2] * inv1, a1[3] * inv1);
      p.y = pack_fp8x4(a1[4] * inv1, a1[5] * inv1, a1[6] * inv1, a1[7] * inv1);
      *(uint2*)(outmean + (size_t)n1 * HID + fl * 8) = p;
    }
  }
}

// ---------------- MFMA GEMM: relu(A1@WL^T + A2@WR^T + b), fp8 A, bf16 W ----------------
// A1/A2 fp8 rows (expanded losslessly to bf16 in staging); WLb/WRb pre-cast
// bf16 (staged by plain uint4 copy). outq != null: fp8 output rows.
// pooled != null: segment-reduce output tile by (sorted) batch id.

__global__ __launch_bounds__(256, 4) void k_gemm_mfma(const unsigned char* __restrict__ A1q,
                                                      const unsigned char* __restrict__ A2q,
                                                      const unsigned short* __restrict__ WLb,
                                                      const unsigned short* __restrict__ WRb,
                                                      const float* __restrict__ bias,
                                                      unsigned char* __restrict__ outq,
                                                      const int* __restrict__ batch,
                                                      float* __restrict__ pooled,
                                                      int M, int relu) {
  __shared__ __align__(16) unsigned short sAB[2 * 128 * LDK];  // sA | sW; reused as sH
  __shared__ int sB[128];
  unsigned short* sA = sAB;
  unsigned short* sW = sAB + 128 * LDK;
  const int t = threadIdx.x;
  const int lane = t & 63;
  const int wave = t >> 6;
  const int row0 = blockIdx.x * 128;
  const int mhalf = (wave & 1) * 64;
  const int nhalf = (wave >> 1) * 64;
  const int ml = lane & 15;
  const int q  = lane >> 4;

  floatx4 acc[4][4];
  #pragma unroll
  for (int a = 0; a < 4; ++a)
    #pragma unroll
    for (int b = 0; b < 4; ++b) acc[a][b] = (floatx4){0.f, 0.f, 0.f, 0.f};

  for (int stage = 0; stage < 4; ++stage) {
    const unsigned char* __restrict__ Aq = (stage < 2) ? A1q : A2q;
    const unsigned short* __restrict__ Wb = (stage < 2) ? WLb : WRb;
    const int k0g = (stage & 1) * 64;
    if (stage) __syncthreads();

    // stage A: 128 rows x 64 fp8 -> bf16 (lossless)
    #pragma unroll
    for (int i = 0; i < 4; ++i) {
      int seg = t + i * 256;
      int r = seg >> 3, kc = (seg & 7) * 8;
      int gr = row0 + r;
      uint2 wv = make_uint2(0u, 0u);
      if (gr < M) wv = *(const uint2*)(Aq + (size_t)gr * HID + k0g + kc);
      *(uint4*)&sA[r * LDK + kc] = fp8x8_to_bf16x8(wv);
    }
    // stage W: 128 rows x 64 bf16, plain uint4 copy
    #pragma unroll
    for (int i = 0; i < 4; ++i) {
      int seg = t + i * 256;
      int o = seg >> 3, kc = (seg & 7) * 8;
      uint4 v = *(const uint4*)(Wb + (size_t)o * HID + k0g + kc);
      *(uint4*)&sW[o * LDK + kc] = v;
    }
    __syncthreads();

    #pragma unroll
    for (int ks = 0; ks < 2; ++ks) {
      int kb = ks * 32 + q * 8;
      short8 af[4], bfr[4];
      #pragma unroll
      for (int mt = 0; mt < 4; ++mt)
        af[mt] = *(const short8*)&sA[(mhalf + mt * 16 + ml) * LDK + kb];
      #pragma unroll
      for (int nt = 0; nt < 4; ++nt)
        bfr[nt] = *(const short8*)&sW[(nhalf + nt * 16 + ml) * LDK + kb];
      #pragma unroll
      for (int mt = 0; mt < 4; ++mt)
        #pragma unroll
        for (int nt = 0; nt < 4; ++nt)
          acc[mt][nt] = __builtin_amdgcn_mfma_f32_16x16x32_bf16(af[mt], bfr[nt], acc[mt][nt], 0, 0, 0);
    }
  }

  if (pooled == nullptr) {
    // C/D layout: col=lane&15, row=q*4+reg
    #pragma unroll
    for (int nt = 0; nt < 4; ++nt) {
      int gcol = nhalf + nt * 16 + ml;
      float bv = bias[gcol];
      #pragma unroll
      for (int mt = 0; mt < 4; ++mt) {
        #pragma unroll
        for (int r = 0; r < 4; ++r) {
          int grow = row0 + mhalf + mt * 16 + q * 4 + r;
          if (grow < M) {
            float v = acc[mt][nt][r] + bv;
            if (relu) v = fmaxf(v, 0.f);
            outq[(size_t)grow * HID + gcol] = f2fp8_one(v);
          }
        }
      }
    }
  } else {
    __syncthreads();
    unsigned short* sH = sAB;
    #pragma unroll
    for (int nt = 0; nt < 4; ++nt) {
      int gcol = nhalf + nt * 16 + ml;
      float bv = bias[gcol];
      #pragma unroll
      for (int mt = 0; mt < 4; ++mt) {
        #pragma unroll
        for (int r = 0; r < 4; ++r) {
          int lr = mhalf + mt * 16 + q * 4 + r;
          float v = acc[mt][nt][r] + bv;
          if (relu) v = fmaxf(v, 0.f);
          sH[lr * 128 + gcol] = f2bf(v);
        }
      }
    }
    if (t < 128) sB[t] = (row0 + t < M) ? batch[row0 + t] : -1;
    __syncthreads();
    const int f = t & 127, half = t >> 7;
    float pacc = 0.f;
    int curg = -1;
    for (int n = half; n < 128; n += 2) {
      int g = sB[n];
      if (g != curg) {
        if (curg >= 0) atomicAdd(&pooled[(size_t)curg * HID + f], pacc);
        curg = g; pacc = 0.f;
      }
      if (g >= 0) pacc += bf2f(sH[n * 128 + f]);
    }
    if (curg >= 0) atomicAdd(&pooled[(size_t)curg * HID + f], pacc);
  }
}

// ---------------- classifier ----------------

__device__ __forceinline__ int lower_bound_dev(const int* a, int n, int key) {
  int lo = 0, hi = n;
  while (lo < hi) {
    int mid = (lo + hi) >> 1;
    if (a[mid] < key) lo = mid + 1; else hi = mid;
  }
  return lo;
}

__global__ __launch_bounds__(256) void k_classify(const float* __restrict__ pooled,
                                                  const int* __restrict__ batch,
                                                  const float* __restrict__ cw,
                                                  const float* __restrict__ cb,
                                                  float* __restrict__ out, int N) {
  __shared__ int bnds[2];
  __shared__ float sp[128];
  __shared__ float part[2][128];
  int g = blockIdx.x;
  int t = threadIdx.x;
  if (t == 0) bnds[0] = lower_bound_dev(batch, N, g);
  if (t == 1) bnds[1] = lower_bound_dev(batch, N, g + 1);
  __syncthreads();
  int cnt = bnds[1] - bnds[0];
  float inv = 1.0f / (float)(cnt > 1 ? cnt : 1);
  if (t < 128) sp[t] = pooled[(size_t)g * HID + t] * inv;
  __syncthreads();
  int o = t & 127, kh = t >> 7;
  float a = 0.f;
  #pragma unroll 4
  for (int k = kh * 64; k < kh * 64 + 64; ++k) a += sp[k] * cw[(size_t)o * HID + k];
  part[kh][o] = a;
  __syncthreads();
  if (t < 128) out[(size_t)g * HID + t] = part[0][t] + part[1][t] + cb[t];
}

// ---------------- launch ----------------

extern "C" void kernel_launch(void* const* d_in, const int* in_sizes, int n_in,
                              void* d_out, int out_size, void* d_ws, size_t ws_size,
                              hipStream_t stream) {
  const float* x     = (const float*)d_in[0];
  const int*   ei    = (const int*)d_in[1];
  const int*   batch = (const int*)d_in[2];
  const float* wl1   = (const float*)d_in[3];
  const float* b1    = (const float*)d_in[4];
  const float* wr1   = (const float*)d_in[5];
  const float* wl2   = (const float*)d_in[6];
  const float* b2    = (const float*)d_in[7];
  const float* wr2   = (const float*)d_in[8];
  const float* cw    = (const float*)d_in[9];
  const float* cb    = (const float*)d_in[10];
  float* out = (float*)d_out;

  const int N = in_sizes[0] / HID;   // 50000 (must be < 65536 for edge packing)
  const int E = in_sizes[1] / 2;     // 800000
  const int G = out_size / HID;      // 128
  const int* src = ei;
  const int* dst = ei + E;

  // workspace layout (fp8 intermediates; bf16 pre-cast weights)
  char* w = (char*)d_ws;
  int*      bcur   = (int*)(w);                    // 256 ints (zeroed)
  float*    pooled = (float*)(w + 1024);           // 16384 fp32 (zeroed) -> ends 66560
  int*      rowbeg = (int*)(w + 66560);            // N ints
  int*      rowend = (int*)(w + 266560);           // N ints
  uint32_t* ebuf   = (uint32_t*)(w + 466944);      // NB*CAP uints (6.42 MB)
  unsigned short* csr16 = (unsigned short*)(w + 6889472);   // NB*CAP ushort (3.2 MB)
  unsigned char* xq    = (unsigned char*)(w + 10100736);             // N*128 fp8 (6.4 MB)
  unsigned char* meanq = (unsigned char*)(w + 10100736 + 6400000);   // N*128 fp8
  unsigned char* h1q   = (unsigned char*)(w + 10100736 + 12800000);  // N*128 fp8
  unsigned short* wb   = (unsigned short*)(w + 10100736 + 19200000); // 4*128*128 bf16 (128 KB)
  unsigned short* wb1l = wb;
  unsigned short* wb1r = wb + HID * HID;
  unsigned short* wb2l = wb + 2 * HID * HID;
  unsigned short* wb2r = wb + 3 * HID * HID;

  const int NB = (N + 255) >> 8;     // 196 buckets
  const int nPairs = (N + 1) / 2;
  const int aggBlocks  = (nPairs + 3) / 4;
  const int gemmBlocks = (N + 127) / 128;
  const int castBlocks = (N * HID / 4 + 255) / 256;
  const int bktBlocks  = (E + EPB - 1) / EPB;

  hipMemsetAsync(w, 0, 66560, stream);   // bcur + pooled

  hipLaunchKernelGGL(k_prologue, dim3(bktBlocks + castBlocks + 64), dim3(256), 0, stream,
                     src, dst, bcur, ebuf, E, NB, x, (uint32_t*)xq, N * HID / 4,
                     bktBlocks, castBlocks, wl1, wr1, wl2, wr2, wb);
  hipLaunchKernelGGL(k_bucket_fill2, dim3(NB), dim3(256), 0, stream, ebuf, bcur, rowbeg, rowend, csr16, N);

  // layer 1 (fp8 gather -> fp8 means; GEMM: fp8 A expanded, bf16 W copied)
  hipLaunchKernelGGL(k_aggregate, dim3(aggBlocks), dim3(256), 0, stream, xq, rowbeg, rowend, csr16, meanq, N);
  hipLaunchKernelGGL(k_gemm_mfma, dim3(gemmBlocks), dim3(256), 0, stream, meanq, xq, wb1l, wb1r, b1, h1q,
                     (const int*)nullptr, (float*)nullptr, N, 1);
  // layer 2 + fused pool
  hipLaunchKernelGGL(k_aggregate, dim3(aggBlocks), dim3(256), 0, stream, h1q, rowbeg, rowend, csr16, meanq, N);
  hipLaunchKernelGGL(k_gemm_mfma, dim3(gemmBlocks), dim3(256), 0, stream, meanq, h1q, wb2l, wb2r, b2,
                     (unsigned char*)nullptr, batch, pooled, N, 1);
  // classifier
  hipLaunchKernelGGL(k_classify, dim3(G), dim3(256), 0, stream, pooled, batch, cw, cb, out, N);
}

// Round 14
// 211.319 us; speedup vs baseline: 1.0579x; 1.0579x over previous
//
#include <hip/hip_runtime.h>
#include <cstdint>
#include <cstddef>

#define HID 128
#define LDK 72    // GEMM LDS row stride in bf16 elems (64 + 8 pad)
#define EPB 4096  // edges per block in bucket pass
#define CAP 8192  // per-bucket capacity in ebuf/csr16 (mean load 4096, sigma ~64)

typedef __attribute__((ext_vector_type(8))) short short8;
typedef __attribute__((ext_vector_type(4))) float floatx4;

#if __has_builtin(__builtin_amdgcn_cvt_pk_f32_fp8) && __has_builtin(__builtin_amdgcn_cvt_pk_fp8_f32)
#define HW_FP8 1
#else
#define HW_FP8 0
#endif

__device__ __forceinline__ unsigned short f2bf(float f) {
  union { float f; uint32_t u; } c; c.f = f;
  uint32_t u = c.u;
  uint32_t r = (u + 0x7FFFu + ((u >> 16) & 1u)) >> 16;   // RNE
  return (unsigned short)r;
}
__device__ __forceinline__ float bf2f(unsigned short s) { return __uint_as_float(((uint32_t)s) << 16); }
// truncating f32->bf16 pair pack — EXACT for fp8-derived values (3-bit mantissa)
__device__ __forceinline__ uint32_t pkbf(float a, float b) {
  return (__float_as_uint(a) >> 16) | (__float_as_uint(b) & 0xFFFF0000u);
}

// Software fp8 e4m3 (OCP) fallback — only used if HW cvt builtins are absent.
__device__ __forceinline__ uint32_t f2fp8_sw(float v) {
  uint32_t u = __float_as_uint(v);
  uint32_t s = (u >> 24) & 0x80u;
  uint32_t af = u & 0x7FFFFFFFu;
  if (__uint_as_float(af) < 0.015625f) return s;
  uint32_t r = af + 0x7FFFFu + ((af >> 20) & 1u);
  return s | ((r >> 20) - 960u);
}
__device__ __forceinline__ float fp8dec_sw(uint32_t b) {
  uint32_t mag = b & 0x7Fu;
  uint32_t v = ((b & 0x80u) << 24) | ((mag << 20) + 0x3C000000u);
  return mag ? __uint_as_float(v) : 0.0f;
}

__device__ __forceinline__ uint32_t pack_fp8x4(float a, float b, float c, float d) {
#if HW_FP8
  int p = __builtin_amdgcn_cvt_pk_fp8_f32(a, b, 0, false);
  p = __builtin_amdgcn_cvt_pk_fp8_f32(c, d, p, true);
  return (uint32_t)p;
#else
  return f2fp8_sw(a) | (f2fp8_sw(b) << 8) | (f2fp8_sw(c) << 16) | (f2fp8_sw(d) << 24);
#endif
}

__device__ __forceinline__ unsigned char f2fp8_one(float v) {
#if HW_FP8
  return (unsigned char)(__builtin_amdgcn_cvt_pk_fp8_f32(v, v, 0, false) & 0xFF);
#else
  return (unsigned char)f2fp8_sw(v);
#endif
}

// accumulate 4 fp8 bytes (one dword) into a[0..3]
__device__ __forceinline__ void acc_fp8x4(float* __restrict__ a, uint32_t w) {
#if HW_FP8
  auto lo = __builtin_amdgcn_cvt_pk_f32_fp8(w, false);
  auto hi = __builtin_amdgcn_cvt_pk_f32_fp8(w, true);
  a[0] += lo[0]; a[1] += lo[1]; a[2] += hi[0]; a[3] += hi[1];
#else
  a[0] += fp8dec_sw(w & 255);
  a[1] += fp8dec_sw((w >> 8) & 255);
  a[2] += fp8dec_sw((w >> 16) & 255);
  a[3] += fp8dec_sw(w >> 24);
#endif
}

// 8 fp8 bytes (uint2) -> 8 bf16 (uint4), lossless expansion
__device__ __forceinline__ uint4 fp8x8_to_bf16x8(uint2 w) {
#if HW_FP8
  auto f01 = __builtin_amdgcn_cvt_pk_f32_fp8(w.x, false);
  auto f23 = __builtin_amdgcn_cvt_pk_f32_fp8(w.x, true);
  auto f45 = __builtin_amdgcn_cvt_pk_f32_fp8(w.y, false);
  auto f67 = __builtin_amdgcn_cvt_pk_f32_fp8(w.y, true);
  uint4 o;
  o.x = pkbf(f01[0], f01[1]);
  o.y = pkbf(f23[0], f23[1]);
  o.z = pkbf(f45[0], f45[1]);
  o.w = pkbf(f67[0], f67[1]);
  return o;
#else
  uint4 o;
  o.x = pkbf(fp8dec_sw(w.x & 255), fp8dec_sw((w.x >> 8) & 255));
  o.y = pkbf(fp8dec_sw((w.x >> 16) & 255), fp8dec_sw(w.x >> 24));
  o.z = pkbf(fp8dec_sw(w.y & 255), fp8dec_sw((w.y >> 8) & 255));
  o.w = pkbf(fp8dec_sw((w.y >> 16) & 255), fp8dec_sw(w.y >> 24));
  return o;
#endif
}

// ---------------- merged prologue: bucket pass + x fp8 cast + weight bf16 cast ----------------
// Blocks [0, bktBlocks): group edges by dst>>8 into per-bucket CAP regions.
// Blocks [bktBlocks, bktBlocks+castBlocks): cast x fp32 -> fp8.
// Blocks [bktBlocks+castBlocks, +64): cast 4 weight matrices fp32 -> bf16 (RNE).

__global__ __launch_bounds__(256) void k_prologue(const int* __restrict__ src,
                                                  const int* __restrict__ dst,
                                                  int* __restrict__ bcur,
                                                  uint32_t* __restrict__ ebuf,
                                                  int E, int NB,
                                                  const float* __restrict__ x,
                                                  uint32_t* __restrict__ xq,
                                                  int n4, int bktBlocks, int castBlocks,
                                                  const float* __restrict__ wl1,
                                                  const float* __restrict__ wr1,
                                                  const float* __restrict__ wl2,
                                                  const float* __restrict__ wr2,
                                                  unsigned short* __restrict__ wb) {
  const int t = threadIdx.x;
  const int bx = (int)blockIdx.x;
  if (bx >= bktBlocks + castBlocks) {
    // weight cast: 16 blocks per matrix, 4 elems/thread
    int wblk = bx - bktBlocks - castBlocks;     // 0..63
    int mat = wblk >> 4;
    const float* wsrc = (mat == 0) ? wl1 : (mat == 1) ? wr1 : (mat == 2) ? wl2 : wr2;
    int i = ((wblk & 15) * 256 + t);            // 0..4095
    float4 v = ((const float4*)wsrc)[i];
    uint32_t lo = (uint32_t)f2bf(v.x) | ((uint32_t)f2bf(v.y) << 16);
    uint32_t hi = (uint32_t)f2bf(v.z) | ((uint32_t)f2bf(v.w) << 16);
    ((uint2*)(wb + (size_t)mat * HID * HID))[i] = make_uint2(lo, hi);
    return;
  }
  if (bx >= bktBlocks) {
    int i = (bx - bktBlocks) * 256 + t;
    if (i < n4) {
      float4 v = ((const float4*)x)[i];
      xq[i] = pack_fp8x4(v.x, v.y, v.z, v.w);
    }
    return;
  }
  __shared__ int hist[256];
  __shared__ int lcur[256];
  const int base = bx * EPB;
  hist[t] = 0;
  __syncthreads();

  uint32_t val[EPB / 256];
  int bk[EPB / 256];
  #pragma unroll
  for (int i = 0; i < EPB / 256; ++i) {
    int e = base + i * 256 + t;
    bk[i] = -1;
    if (e < E) {
      int d = dst[e];
      int s = src[e];
      bk[i] = d >> 8;
      val[i] = (uint32_t)s | ((uint32_t)(d & 255) << 16);
      atomicAdd(&hist[bk[i]], 1);
    }
  }
  __syncthreads();
  if (t < NB) {
    int c = hist[t];
    lcur[t] = c ? atomicAdd(&bcur[t], c) : 0;
  }
  __syncthreads();
  #pragma unroll
  for (int i = 0; i < EPB / 256; ++i) {
    if (bk[i] >= 0) {
      int pos = bk[i] * CAP + atomicAdd(&lcur[bk[i]], 1);
      ebuf[pos] = val[i];
    }
  }
}

// fill pass: one block per bucket; builds rowbeg/rowend + csr16 in CAP region.
__global__ __launch_bounds__(256) void k_bucket_fill2(const uint32_t* __restrict__ ebuf,
                                                      const int* __restrict__ bcur,
                                                      int* __restrict__ rowbeg,
                                                      int* __restrict__ rowend,
                                                      unsigned short* __restrict__ csr16,
                                                      int N) {
  __shared__ int hist[256];
  __shared__ int scan[256];
  const int b = blockIdx.x;
  const int t = threadIdx.x;
  hist[t] = 0;
  __syncthreads();
  const int lo = b * CAP;
  const int hi = lo + bcur[b];
  for (int i = lo + t; i < hi; i += 256) atomicAdd(&hist[ebuf[i] >> 16], 1);
  __syncthreads();
  int v = hist[t];
  scan[t] = v;
  __syncthreads();
  #pragma unroll
  for (int off = 1; off < 256; off <<= 1) {
    int add = (t >= off) ? scan[t - off] : 0;
    __syncthreads();
    scan[t] += add;
    __syncthreads();
  }
  int excl = scan[t] - v;
  int node = (b << 8) + t;
  if (node < N) {
    rowbeg[node] = lo + excl;
    rowend[node] = lo + excl + v;
  }
  hist[t] = lo + excl;   // reuse as cursor
  __syncthreads();
  for (int i = lo + t; i < hi; i += 256) {
    uint32_t e = ebuf[i];
    int pos = atomicAdd(&hist[e >> 16], 1);
    csr16[pos] = (unsigned short)(e & 0xFFFFu);
  }
}

// ---------------- mean aggregation: one wave per TWO nodes, fp8 in/out ----------------

__global__ __launch_bounds__(256) void k_aggregate(const unsigned char* __restrict__ featq,
                                                   const int* __restrict__ rowbeg,
                                                   const int* __restrict__ rowend,
                                                   const unsigned short* __restrict__ csr16,
                                                   unsigned char* __restrict__ outmean, int N) {
  int wpair = blockIdx.x * 4 + (threadIdx.x >> 6);
  int n0 = wpair * 2;
  int n1 = n0 + 1;
  int lane = threadIdx.x & 63;
  if (n0 >= N) return;
  const int grp = lane >> 4;
  const int fl  = lane & 15;

  int b0 = rowbeg[n0], e0 = rowend[n0];
  int b1 = 0, e1 = 0;
  if (n1 < N) { b1 = rowbeg[n1]; e1 = rowend[n1]; }
  const int d0 = e0 - b0, d1 = e1 - b1;

  float a0[8], a1[8];
  #pragma unroll
  for (int i = 0; i < 8; ++i) { a0[i] = 0.f; a1[i] = 0.f; }

  while (b0 < e0 || b1 < e1) {
    int m0 = e0 - b0; if (m0 < 0) m0 = 0; if (m0 > 64) m0 = 64;
    int m1 = e1 - b1; if (m1 < 0) m1 = 0; if (m1 > 64) m1 = 64;
    int sidx0 = (b0 + lane < e0) ? (int)csr16[b0 + lane] : 0;
    int sidx1 = (b1 + lane < e1) ? (int)csr16[b1 + lane] : 0;
    int mm = m0 > m1 ? m0 : m1;
    for (int j = 0; j < mm; j += 16) {
      int j0 = j + grp, j1 = j + grp + 4, j2 = j + grp + 8, j3 = j + grp + 12;
      int s00 = __shfl(sidx0, j0, 64), s01 = __shfl(sidx0, j1, 64);
      int s02 = __shfl(sidx0, j2, 64), s03 = __shfl(sidx0, j3, 64);
      int s10 = __shfl(sidx1, j0, 64), s11 = __shfl(sidx1, j1, 64);
      int s12 = __shfl(sidx1, j2, 64), s13 = __shfl(sidx1, j3, 64);
      bool p00 = j0 < m0, p01 = j1 < m0, p02 = j2 < m0, p03 = j3 < m0;
      bool p10 = j0 < m1, p11 = j1 < m1, p12 = j2 < m1, p13 = j3 < m1;
      uint2 u00, u01, u02, u03, u10, u11, u12, u13;
      if (p00) u00 = *(const uint2*)(featq + (size_t)s00 * HID + fl * 8);
      if (p01) u01 = *(const uint2*)(featq + (size_t)s01 * HID + fl * 8);
      if (p02) u02 = *(const uint2*)(featq + (size_t)s02 * HID + fl * 8);
      if (p03) u03 = *(const uint2*)(featq + (size_t)s03 * HID + fl * 8);
      if (p10) u10 = *(const uint2*)(featq + (size_t)s10 * HID + fl * 8);
      if (p11) u11 = *(const uint2*)(featq + (size_t)s11 * HID + fl * 8);
      if (p12) u12 = *(const uint2*)(featq + (size_t)s12 * HID + fl * 8);
      if (p13) u13 = *(const uint2*)(featq + (size_t)s13 * HID + fl * 8);
      if (p00) { acc_fp8x4(a0, u00.x); acc_fp8x4(a0 + 4, u00.y); }
      if (p01) { acc_fp8x4(a0, u01.x); acc_fp8x4(a0 + 4, u01.y); }
      if (p02) { acc_fp8x4(a0, u02.x); acc_fp8x4(a0 + 4, u02.y); }
      if (p03) { acc_fp8x4(a0, u03.x); acc_fp8x4(a0 + 4, u03.y); }
      if (p10) { acc_fp8x4(a1, u10.x); acc_fp8x4(a1 + 4, u10.y); }
      if (p11) { acc_fp8x4(a1, u11.x); acc_fp8x4(a1 + 4, u11.y); }
      if (p12) { acc_fp8x4(a1, u12.x); acc_fp8x4(a1 + 4, u12.y); }
      if (p13) { acc_fp8x4(a1, u13.x); acc_fp8x4(a1 + 4, u13.y); }
    }
    b0 += 64; b1 += 64;
  }

  #pragma unroll
  for (int i = 0; i < 8; ++i) {
    a0[i] += __shfl_xor(a0[i], 16, 64);
    a0[i] += __shfl_xor(a0[i], 32, 64);
    a1[i] += __shfl_xor(a1[i], 16, 64);
    a1[i] += __shfl_xor(a1[i], 32, 64);
  }
  if (grp == 0) {
    float inv0 = 1.0f / (float)(d0 > 1 ? d0 : 1);
    uint2 o;
    o.x = pack_fp8x4(a0[0] * inv0, a0[1] * inv0, a0[2] * inv0, a0[3] * inv0);
    o.y = pack_fp8x4(a0[4] * inv0, a0[5] * inv0, a0[6] * inv0, a0[7] * inv0);
    *(uint2*)(outmean + (size_t)n0 * HID + fl * 8) = o;
    if (n1 < N) {
      float inv1 = 1.0f / (float)(d1 > 1 ? d1 : 1);
      uint2 p;
      p.x = pack_fp8x4(a1[0] * inv1, a1[1] * inv1, a1[2] * inv1, a1[3] * inv1);
      p.y = pack_fp8x4(a1[4] * inv1, a1[5] * inv1, a1[6] * inv1, a1[7] * inv1);
      *(uint2*)(outmean + (size_t)n1 * HID + fl * 8) = p;
    }
  }
}

// ---------------- MFMA GEMM: relu(A1@WL^T + A2@WR^T + b), fp8 A, bf16 W ----------------
// launch_bounds (256,2): LDS (73.7KB) caps at 2 blocks/CU anyway; (256,4)
// strangled the register allocator (R13 regression, +8µs).

__global__ __launch_bounds__(256, 2) void k_gemm_mfma(const unsigned char* __restrict__ A1q,
                                                      const unsigned char* __restrict__ A2q,
                                                      const unsigned short* __restrict__ WLb,
                                                      const unsigned short* __restrict__ WRb,
                                                      const float* __restrict__ bias,
                                                      unsigned char* __restrict__ outq,
                                                      const int* __restrict__ batch,
                                                      float* __restrict__ pooled,
                                                      int M, int relu) {
  __shared__ __align__(16) unsigned short sAB[2 * 128 * LDK];  // sA | sW; reused as sH
  __shared__ int sB[128];
  unsigned short* sA = sAB;
  unsigned short* sW = sAB + 128 * LDK;
  const int t = threadIdx.x;
  const int lane = t & 63;
  const int wave = t >> 6;
  const int row0 = blockIdx.x * 128;
  const int mhalf = (wave & 1) * 64;
  const int nhalf = (wave >> 1) * 64;
  const int ml = lane & 15;
  const int q  = lane >> 4;

  floatx4 acc[4][4];
  #pragma unroll
  for (int a = 0; a < 4; ++a)
    #pragma unroll
    for (int b = 0; b < 4; ++b) acc[a][b] = (floatx4){0.f, 0.f, 0.f, 0.f};

  for (int stage = 0; stage < 4; ++stage) {
    const unsigned char* __restrict__ Aq = (stage < 2) ? A1q : A2q;
    const unsigned short* __restrict__ Wb = (stage < 2) ? WLb : WRb;
    const int k0g = (stage & 1) * 64;
    if (stage) __syncthreads();

    // stage A: 128 rows x 64 fp8 -> bf16 (lossless)
    #pragma unroll
    for (int i = 0; i < 4; ++i) {
      int seg = t + i * 256;
      int r = seg >> 3, kc = (seg & 7) * 8;
      int gr = row0 + r;
      uint2 wv = make_uint2(0u, 0u);
      if (gr < M) wv = *(const uint2*)(Aq + (size_t)gr * HID + k0g + kc);
      *(uint4*)&sA[r * LDK + kc] = fp8x8_to_bf16x8(wv);
    }
    // stage W: 128 rows x 64 bf16, plain uint4 copy
    #pragma unroll
    for (int i = 0; i < 4; ++i) {
      int seg = t + i * 256;
      int o = seg >> 3, kc = (seg & 7) * 8;
      uint4 v = *(const uint4*)(Wb + (size_t)o * HID + k0g + kc);
      *(uint4*)&sW[o * LDK + kc] = v;
    }
    __syncthreads();

    #pragma unroll
    for (int ks = 0; ks < 2; ++ks) {
      int kb = ks * 32 + q * 8;
      short8 af[4], bfr[4];
      #pragma unroll
      for (int mt = 0; mt < 4; ++mt)
        af[mt] = *(const short8*)&sA[(mhalf + mt * 16 + ml) * LDK + kb];
      #pragma unroll
      for (int nt = 0; nt < 4; ++nt)
        bfr[nt] = *(const short8*)&sW[(nhalf + nt * 16 + ml) * LDK + kb];
      #pragma unroll
      for (int mt = 0; mt < 4; ++mt)
        #pragma unroll
        for (int nt = 0; nt < 4; ++nt)
          acc[mt][nt] = __builtin_amdgcn_mfma_f32_16x16x32_bf16(af[mt], bfr[nt], acc[mt][nt], 0, 0, 0);
    }
  }

  if (pooled == nullptr) {
    // C/D layout: col=lane&15, row=q*4+reg
    #pragma unroll
    for (int nt = 0; nt < 4; ++nt) {
      int gcol = nhalf + nt * 16 + ml;
      float bv = bias[gcol];
      #pragma unroll
      for (int mt = 0; mt < 4; ++mt) {
        #pragma unroll
        for (int r = 0; r < 4; ++r) {
          int grow = row0 + mhalf + mt * 16 + q * 4 + r;
          if (grow < M) {
            float v = acc[mt][nt][r] + bv;
            if (relu) v = fmaxf(v, 0.f);
            outq[(size_t)grow * HID + gcol] = f2fp8_one(v);
          }
        }
      }
    }
  } else {
    __syncthreads();
    unsigned short* sH = sAB;
    #pragma unroll
    for (int nt = 0; nt < 4; ++nt) {
      int gcol = nhalf + nt * 16 + ml;
      float bv = bias[gcol];
      #pragma unroll
      for (int mt = 0; mt < 4; ++mt) {
        #pragma unroll
        for (int r = 0; r < 4; ++r) {
          int lr = mhalf + mt * 16 + q * 4 + r;
          float v = acc[mt][nt][r] + bv;
          if (relu) v = fmaxf(v, 0.f);
          sH[lr * 128 + gcol] = f2bf(v);
        }
      }
    }
    if (t < 128) sB[t] = (row0 + t < M) ? batch[row0 + t] : -1;
    __syncthreads();
    const int f = t & 127, half = t >> 7;
    float pacc = 0.f;
    int curg = -1;
    for (int n = half; n < 128; n += 2) {
      int g = sB[n];
      if (g != curg) {
        if (curg >= 0) atomicAdd(&pooled[(size_t)curg * HID + f], pacc);
        curg = g; pacc = 0.f;
      }
      if (g >= 0) pacc += bf2f(sH[n * 128 + f]);
    }
    if (curg >= 0) atomicAdd(&pooled[(size_t)curg * HID + f], pacc);
  }
}

// ---------------- classifier ----------------

__device__ __forceinline__ int lower_bound_dev(const int* a, int n, int key) {
  int lo = 0, hi = n;
  while (lo < hi) {
    int mid = (lo + hi) >> 1;
    if (a[mid] < key) lo = mid + 1; else hi = mid;
  }
  return lo;
}

__global__ __launch_bounds__(256) void k_classify(const float* __restrict__ pooled,
                                                  const int* __restrict__ batch,
                                                  const float* __restrict__ cw,
                                                  const float* __restrict__ cb,
                                                  float* __restrict__ out, int N) {
  __shared__ int bnds[2];
  __shared__ float sp[128];
  __shared__ float part[2][128];
  int g = blockIdx.x;
  int t = threadIdx.x;
  if (t == 0) bnds[0] = lower_bound_dev(batch, N, g);
  if (t == 1) bnds[1] = lower_bound_dev(batch, N, g + 1);
  __syncthreads();
  int cnt = bnds[1] - bnds[0];
  float inv = 1.0f / (float)(cnt > 1 ? cnt : 1);
  if (t < 128) sp[t] = pooled[(size_t)g * HID + t] * inv;
  __syncthreads();
  int o = t & 127, kh = t >> 7;
  float a = 0.f;
  #pragma unroll 4
  for (int k = kh * 64; k < kh * 64 + 64; ++k) a += sp[k] * cw[(size_t)o * HID + k];
  part[kh][o] = a;
  __syncthreads();
  if (t < 128) out[(size_t)g * HID + t] = part[0][t] + part[1][t] + cb[t];
}

// ---------------- launch ----------------

extern "C" void kernel_launch(void* const* d_in, const int* in_sizes, int n_in,
                              void* d_out, int out_size, void* d_ws, size_t ws_size,
                              hipStream_t stream) {
  const float* x     = (const float*)d_in[0];
  const int*   ei    = (const int*)d_in[1];
  const int*   batch = (const int*)d_in[2];
  const float* wl1   = (const float*)d_in[3];
  const float* b1    = (const float*)d_in[4];
  const float* wr1   = (const float*)d_in[5];
  const float* wl2   = (const float*)d_in[6];
  const float* b2    = (const float*)d_in[7];
  const float* wr2   = (const float*)d_in[8];
  const float* cw    = (const float*)d_in[9];
  const float* cb    = (const float*)d_in[10];
  float* out = (float*)d_out;

  const int N = in_sizes[0] / HID;   // 50000 (must be < 65536 for edge packing)
  const int E = in_sizes[1] / 2;     // 800000
  const int G = out_size / HID;      // 128
  const int* src = ei;
  const int* dst = ei + E;

  // workspace layout (fp8 intermediates; bf16 pre-cast weights)
  char* w = (char*)d_ws;
  int*      bcur   = (int*)(w);                    // 256 ints (zeroed)
  float*    pooled = (float*)(w + 1024);           // 16384 fp32 (zeroed) -> ends 66560
  int*      rowbeg = (int*)(w + 66560);            // N ints
  int*      rowend = (int*)(w + 266560);           // N ints
  uint32_t* ebuf   = (uint32_t*)(w + 466944);      // NB*CAP uints (6.42 MB)
  unsigned short* csr16 = (unsigned short*)(w + 6889472);   // NB*CAP ushort (3.2 MB)
  unsigned char* xq    = (unsigned char*)(w + 10100736);             // N*128 fp8 (6.4 MB)
  unsigned char* meanq = (unsigned char*)(w + 10100736 + 6400000);   // N*128 fp8
  unsigned char* h1q   = (unsigned char*)(w + 10100736 + 12800000);  // N*128 fp8
  unsigned short* wb   = (unsigned short*)(w + 10100736 + 19200000); // 4*128*128 bf16
  unsigned short* wb1l = wb;
  unsigned short* wb1r = wb + HID * HID;
  unsigned short* wb2l = wb + 2 * HID * HID;
  unsigned short* wb2r = wb + 3 * HID * HID;

  const int NB = (N + 255) >> 8;     // 196 buckets
  const int nPairs = (N + 1) / 2;
  const int aggBlocks  = (nPairs + 3) / 4;
  const int gemmBlocks = (N + 127) / 128;
  const int castBlocks = (N * HID / 4 + 255) / 256;
  const int bktBlocks  = (E + EPB - 1) / EPB;

  hipMemsetAsync(w, 0, 66560, stream);   // bcur + pooled

  hipLaunchKernelGGL(k_prologue, dim3(bktBlocks + castBlocks + 64), dim3(256), 0, stream,
                     src, dst, bcur, ebuf, E, NB, x, (uint32_t*)xq, N * HID / 4,
                     bktBlocks, castBlocks, wl1, wr1, wl2, wr2, wb);
  hipLaunchKernelGGL(k_bucket_fill2, dim3(NB), dim3(256), 0, stream, ebuf, bcur, rowbeg, rowend, csr16, N);

  // layer 1 (fp8 gather -> fp8 means; GEMM: fp8 A expanded, bf16 W copied)
  hipLaunchKernelGGL(k_aggregate, dim3(aggBlocks), dim3(256), 0, stream, xq, rowbeg, rowend, csr16, meanq, N);
  hipLaunchKernelGGL(k_gemm_mfma, dim3(gemmBlocks), dim3(256), 0, stream, meanq, xq, wb1l, wb1r, b1, h1q,
                     (const int*)nullptr, (float*)nullptr, N, 1);
  // layer 2 + fused pool
  hipLaunchKernelGGL(k_aggregate, dim3(aggBlocks), dim3(256), 0, stream, h1q, rowbeg, rowend, csr16, meanq, N);
  hipLaunchKernelGGL(k_gemm_mfma, dim3(gemmBlocks), dim3(256), 0, stream, meanq, h1q, wb2l, wb2r, b2,
                     (unsigned char*)nullptr, batch, pooled, N, 1);
  // classifier
  hipLaunchKernelGGL(k_classify, dim3(G), dim3(256), 0, stream, pooled, batch, cw, cb, out, N);
}